// Round 4
// baseline (336.317 us; speedup 1.0000x reference)
//
#include <hip/hip_runtime.h>
#include <stdint.h>
#include <math.h>

#define NB 64      // batch
#define BT 512     // time steps
#define NH 768     // hidden
#define NL 9       // labels
#define PADW 772   // padded W row stride (floats): (l*772+h)%32 spreads banks
#define BPB 8      // batches per crf block
#define BPROW 16   // bp_lds row stride in bytes

__device__ __forceinline__ float rlane(float v, int i) {
    return __int_as_float(__builtin_amdgcn_readlane(__float_as_int(v), i));
}
__device__ __forceinline__ uint32_t rlane_u(uint32_t v, int i) {
    return (uint32_t)__builtin_amdgcn_readlane((int)v, i);
}

// DPP-based cross-lane add: v += dpp_move(v); runs on VALU, NOT the DS pipe.
template<int CTRL, int RM>
__device__ __forceinline__ float dppadd(float v) {
    const int t = __builtin_amdgcn_update_dpp(0, __float_as_int(v), CTRL, RM, 0xf, true);
    return v + __int_as_float(t);
}

// full 64-lane sum -> uniform scalar (read from lane 63)
__device__ __forceinline__ float wave_sum_dpp(float v) {
    v = dppadd<0x111, 0xf>(v);   // row_shr:1
    v = dppadd<0x112, 0xf>(v);   // row_shr:2
    v = dppadd<0x114, 0xf>(v);   // row_shr:4
    v = dppadd<0x118, 0xf>(v);   // row_shr:8
    v = dppadd<0x142, 0xa>(v);   // row_bcast:15 into rows 1,3
    v = dppadd<0x143, 0xc>(v);   // row_bcast:31 into rows 2,3 -> lane 63 = total
    return rlane(v, 63);
}

// ---------------------------------------------------------------------------
// Kernel 1: logits = x @ W + b.  Wave-per-row, W register-cached from LDS.
// Depth-2 row prefetch.
// ---------------------------------------------------------------------------
__global__ __launch_bounds__(256, 2) void gemm_kernel(
    const float* __restrict__ x, const float* __restrict__ W,
    const float* __restrict__ bias, float* __restrict__ logits)
{
    __shared__ float wT[NL * PADW];   // 27.8 KB: W transposed [l][h], padded

    const int tid  = threadIdx.x;
    const int lane = tid & 63;

    for (int i = tid; i < NH * NL; i += 256) {
        const int h = i / NL, l = i - h * NL;
        wT[l * PADW + h] = W[i];
    }
    __syncthreads();

    float wr[3][NL][4];
#pragma unroll
    for (int k = 0; k < 3; ++k)
#pragma unroll
        for (int l = 0; l < NL; ++l) {
            const float4 w4 = *(const float4*)&wT[l * PADW + k * 256 + lane * 4];
            wr[k][l][0] = w4.x; wr[k][l][1] = w4.y;
            wr[k][l][2] = w4.z; wr[k][l][3] = w4.w;
        }
    const float bj = bias[lane < NL ? lane : 0];

    const int gwave = (blockIdx.x * blockDim.x + tid) >> 6;
    const int nw    = (gridDim.x * blockDim.x) >> 6;
    const int nrows = NB * BT;
    int row = gwave;
    if (row >= nrows) return;

    const float4* xr = (const float4*)(x + (size_t)row * NH);
    float4 a0 = xr[lane], a1 = xr[64 + lane], a2 = xr[128 + lane];

    int r1 = row + nw;
    float4 b0{}, b1{}, b2{};
    if (r1 < nrows) {
        const float4* xn = (const float4*)(x + (size_t)r1 * NH);
        b0 = xn[lane]; b1 = xn[64 + lane]; b2 = xn[128 + lane];
    }

    while (true) {
        const int r2 = r1 + nw;
        float4 c0{}, c1{}, c2{};
        if (r2 < nrows) {
            const float4* xn = (const float4*)(x + (size_t)r2 * NH);
            c0 = xn[lane]; c1 = xn[64 + lane]; c2 = xn[128 + lane];
        }

        float acc[NL];
#pragma unroll
        for (int l = 0; l < NL; ++l) {
            float s = a0.x * wr[0][l][0];
            s = fmaf(a0.y, wr[0][l][1], s);
            s = fmaf(a0.z, wr[0][l][2], s);
            s = fmaf(a0.w, wr[0][l][3], s);
            s = fmaf(a1.x, wr[1][l][0], s);
            s = fmaf(a1.y, wr[1][l][1], s);
            s = fmaf(a1.z, wr[1][l][2], s);
            s = fmaf(a1.w, wr[1][l][3], s);
            s = fmaf(a2.x, wr[2][l][0], s);
            s = fmaf(a2.y, wr[2][l][1], s);
            s = fmaf(a2.z, wr[2][l][2], s);
            s = fmaf(a2.w, wr[2][l][3], s);
            acc[l] = s;
        }
        float sum[NL];
#pragma unroll
        for (int l = 0; l < NL; ++l) sum[l] = wave_sum_dpp(acc[l]);
        float outv = sum[0];
#pragma unroll
        for (int l = 1; l < NL; ++l) outv = (lane == l) ? sum[l] : outv;
        if (lane < NL) logits[(size_t)row * NL + lane] = outv + bj;

        if (r1 >= nrows) break;
        a0 = b0; a1 = b1; a2 = b2;
        b0 = c0; b1 = c1; b2 = c2;
        row = r1; r1 = r2;
    }
}

// ---------------------------------------------------------------------------
// Kernel 2: CRF.  8 blocks x 1024 threads, 8 batches/block.
// 16 waves/block = 8 logZ + 8 viterbi -> 4 independent scan chains per SIMD
// (was 1/SIMD at 64 blocks x 4 waves -> every chain instr paid full latency,
// VALUBusy 3.3%).  Scans read logits from global/L3 with one-block-ahead
// prefetch (loads never on the chain).  Backpointers computed INLINE in the
// viterbi wave (bit-exact first-argmax) -> no val_lds, no recompute pass.
// ---------------------------------------------------------------------------
__global__ __launch_bounds__(1024) void crf_kernel(
    const float* __restrict__ logits, const float* __restrict__ trans,
    const int* __restrict__ label, const int* __restrict__ seqlen,
    float* __restrict__ vit_out, float* __restrict__ stats)
{
    __shared__ uint8_t  bp_lds[BPB * (BT - 1) * BPROW];   // 65408 B
    __shared__ uint64_t packed_lds[BPB * (BT - 1)];       // 32704 B
    __shared__ uint8_t  vit_lds[BPB * BT];                //  4096 B

    const int tid  = threadIdx.x;
    const int lane = tid & 63;
    const int wv   = tid >> 6;          // 0..15
    const int w    = wv & 7;            // batch slot within block
    const int b    = blockIdx.x * BPB + w;
    const int sl   = seqlen[b];
    const float* lg  = logits + (size_t)b * BT * NL;
    const int*   lab = label + (size_t)b * BT;
    const int j = lane < NL ? lane : 0;

    if (wv < 8) {
        // ---- logZ scan, scaled-exp domain ----
        float E[NL];
#pragma unroll
        for (int i = 0; i < NL; ++i) E[i] = __expf(trans[i * NL + j]) * 0.125f;
        float A = __expf(lg[j]);
        int lc = 0;
        float cur[8], nxt[8];
#pragma unroll
        for (int s = 0; s < 8; ++s) cur[s] = lg[(1 + s) * NL + j];
        for (int tb = 1; tb < BT + 8; tb += 8) {
            // prefetch next 8-step block (clamped addresses; values masked)
#pragma unroll
            for (int s = 0; s < 8; ++s) {
                int tt = tb + 8 + s; if (tt > BT - 1) tt = BT - 1;
                nxt[s] = lg[tt * NL + j];
            }
            float P[8];
#pragma unroll
            for (int s = 0; s < 8; ++s) P[s] = __expf(cur[s]);
#pragma unroll
            for (int s = 0; s < 8; ++s) {
                const int t = tb + s;
                const float r0 = rlane(A, 0), r1 = rlane(A, 1), r2 = rlane(A, 2),
                            r3 = rlane(A, 3), r4 = rlane(A, 4), r5 = rlane(A, 5),
                            r6 = rlane(A, 6), r7 = rlane(A, 7), r8 = rlane(A, 8);
                float p0 = r0 * E[0]; p0 = fmaf(r1, E[1], p0); p0 = fmaf(r2, E[2], p0);
                float p1 = r3 * E[3]; p1 = fmaf(r4, E[4], p1); p1 = fmaf(r5, E[5], p1);
                float p2 = r6 * E[6]; p2 = fmaf(r7, E[7], p2); p2 = fmaf(r8, E[8], p2);
                const float An = ((p0 + p1) + p2) * P[s];
                A = (t < sl) ? An : A;
            }
            // exact pow2 renorm: m is positive & normal here.
            const float m = fmaxf(
                fmaxf(fmaxf(fmaxf(rlane(A, 0), rlane(A, 1)), rlane(A, 2)),
                      fmaxf(fmaxf(rlane(A, 3), rlane(A, 4)), rlane(A, 5))),
                fmaxf(fmaxf(rlane(A, 6), rlane(A, 7)), rlane(A, 8)));
            const int ex = (int)((__float_as_uint(m) >> 23) & 0xFFu) - 126;
            const float sc = __uint_as_float((uint32_t)(127 - ex) << 23);
            A *= sc;
            lc += ex;
#pragma unroll
            for (int s = 0; s < 8; ++s) cur[s] = nxt[s];
        }
        const float sum = ((rlane(A, 0) + rlane(A, 1)) + (rlane(A, 2) + rlane(A, 3))) +
                          ((rlane(A, 4) + rlane(A, 5)) + (rlane(A, 6) + rlane(A, 7))) +
                          rlane(A, 8);
        const float logZ = logf(sum) +
            ((float)lc + 3.0f * (float)(sl - 1)) * 0.6931471805599453f;
        if (lane == 0) stats[b * 8 + 1] = logZ;
    } else {
        // ---- viterbi value scan + INLINE backpointers ----
        float tc[NL];
#pragma unroll
        for (int i = 0; i < NL; ++i) tc[i] = trans[i * NL + j];
        float v = lg[j];
        float cur[8], nxt[8];
#pragma unroll
        for (int s = 0; s < 8; ++s) cur[s] = lg[(1 + s) * NL + j];
        for (int tb = 1; tb < BT + 8; tb += 8) {
#pragma unroll
            for (int s = 0; s < 8; ++s) {
                int tt = tb + 8 + s; if (tt > BT - 1) tt = BT - 1;
                nxt[s] = lg[tt * NL + j];
            }
#pragma unroll
            for (int s = 0; s < 8; ++s) {
                const int t = tb + s;
                const float r0 = rlane(v, 0), r1 = rlane(v, 1), r2 = rlane(v, 2),
                            r3 = rlane(v, 3), r4 = rlane(v, 4), r5 = rlane(v, 5),
                            r6 = rlane(v, 6), r7 = rlane(v, 7), r8 = rlane(v, 8);
                const float c0 = r0 + tc[0], c1 = r1 + tc[1], c2 = r2 + tc[2],
                            c3 = r3 + tc[3], c4 = r4 + tc[4], c5 = r5 + tc[5],
                            c6 = r6 + tc[6], c7 = r7 + tc[7], c8 = r8 + tc[8];
                const float m = fmaxf(
                    fmaxf(fmaxf(fmaxf(c0, c1), c2), fmaxf(fmaxf(c3, c4), c5)),
                    fmaxf(fmaxf(c6, c7), c8));
                const float nv = m + cur[s];
                v = (t < sl) ? nv : v;
                // first-argmax over i (bit-exact: values identical to ref's)
                int bi = 8;
                bi = (c7 == m) ? 7 : bi;
                bi = (c6 == m) ? 6 : bi;
                bi = (c5 == m) ? 5 : bi;
                bi = (c4 == m) ? 4 : bi;
                bi = (c3 == m) ? 3 : bi;
                bi = (c2 == m) ? 2 : bi;
                bi = (c1 == m) ? 1 : bi;
                bi = (c0 == m) ? 0 : bi;
                bi = (t < sl) ? bi : j;      // identity past seqlen
                if (lane < NL && t < BT)
                    bp_lds[(w * (BT - 1) + (t - 1)) * BPROW + lane] = (uint8_t)bi;
            }
#pragma unroll
            for (int s = 0; s < 8; ++s) cur[s] = nxt[s];
        }
        // last tag = first-argmax(alphaT)
        const float r0 = rlane(v, 0), r1 = rlane(v, 1), r2 = rlane(v, 2),
                    r3 = rlane(v, 3), r4 = rlane(v, 4), r5 = rlane(v, 5),
                    r6 = rlane(v, 6), r7 = rlane(v, 7), r8 = rlane(v, 8);
        const float m = fmaxf(
            fmaxf(fmaxf(fmaxf(r0, r1), r2), fmaxf(fmaxf(r3, r4), r5)),
            fmaxf(fmaxf(r6, r7), r8));
        const int last = (r0 == m) ? 0 : (r1 == m) ? 1 : (r2 == m) ? 2 :
                         (r3 == m) ? 3 : (r4 == m) ? 4 : (r5 == m) ? 5 :
                         (r6 == m) ? 6 : (r7 == m) ? 7 : 8;
        if (lane == 0) vit_lds[w * BT + BT - 1] = (uint8_t)last;
    }
    __syncthreads();

    // ---- pack bp rows: 9 x 4 bits -> u64 (all 16 waves) ----
    for (int idx = tid; idx < BPB * (BT - 1); idx += 1024) {
        const int base = idx * BPROW;
        uint64_t p = 0;
#pragma unroll
        for (int i = 0; i < NL; ++i)
            p |= (uint64_t)bp_lds[base + i] << (4 * i);
        packed_lds[idx] = p;
    }
    __syncthreads();

    if (wv < 8) {
        // ---- register-resident backtrack for batch slot w ----
        uint32_t plo[8], phi[8];
#pragma unroll
        for (int r = 0; r < 8; ++r) {
            const int t = r * 64 + lane;
            uint64_t val = 0;
            if (t < BT - 1) val = packed_lds[w * (BT - 1) + t];
            plo[r] = (uint32_t)val;
            phi[r] = (uint32_t)(val >> 32);
        }
        int tag = vit_lds[w * BT + BT - 1];
#pragma unroll
        for (int r = 7; r >= 0; --r) {
            const int lhi = (r == 7) ? 62 : 63;   // t = 511 has no bp row
#pragma unroll 4
            for (int l = lhi; l >= 0; --l) {
                const uint32_t lo = rlane_u(plo[r], l);   // uniform SGPR index,
                const uint32_t hi = rlane_u(phi[r], l);   // independent of tag
                const uint32_t ww = (tag & 8) ? hi : lo;
                tag = (int)((ww >> ((4 * tag) & 31)) & 15u);
                if (lane == 0) vit_lds[w * BT + r * 64 + l] = (uint8_t)tag;
            }
        }
    } else {
        // ---- gold-path score for batch slot w (runs parallel to backtrack) ----
        int labv[8];
#pragma unroll
        for (int k = 0; k < 8; ++k) labv[k] = lab[lane + 64 * k];
        float s = 0.f;
#pragma unroll
        for (int k = 0; k < 8; ++k) {
            const int t = lane + 64 * k;
            if (t < sl) {
                s += lg[t * NL + labv[k]];
                if (t >= 1) s += trans[lab[t - 1] * NL + labv[k]];
            }
        }
#pragma unroll
        for (int off = 32; off >= 1; off >>= 1) s += __shfl_xor(s, off, 64);
        if (lane == 0) stats[b * 8 + 0] = s;
    }
    __syncthreads();

    // ---- stats + vit output: wave w handles batch slot w ----
    if (wv < 8) {
        float accv = 0.f, tpv = 0.f, tnv = 0.f, fpv = 0.f;
#pragma unroll
        for (int k = 0; k < 8; ++k) {
            const int t = lane + 64 * k;
            const int tg = vit_lds[w * BT + t];
            const int lb = lab[t];
            const bool msk = t < sl;
            vit_out[(size_t)b * BT + t] = (float)tg;
            if (msk && tg == lb) accv += 1.f;
            if (lb > 0 && tg == lb) tpv += 1.f;
            if (lb > 0 && tg != lb) tnv += 1.f;
            if (msk && lb == 0 && tg > 0) fpv += 1.f;
        }
#pragma unroll
        for (int off = 32; off >= 1; off >>= 1) {
            accv += __shfl_xor(accv, off, 64);
            tpv  += __shfl_xor(tpv,  off, 64);
            tnv  += __shfl_xor(tnv,  off, 64);
            fpv  += __shfl_xor(fpv,  off, 64);
        }
        if (lane == 0) {
            stats[b * 8 + 2] = accv;
            stats[b * 8 + 3] = tpv;
            stats[b * 8 + 4] = tnv;
            stats[b * 8 + 5] = fpv;
        }
    }
}

// ---------------------------------------------------------------------------
// Kernel 3: reduce the 64 per-batch partials -> tp, tn, fp, loss, accuracy
// ---------------------------------------------------------------------------
__global__ __launch_bounds__(64) void finalize_kernel(
    const float* __restrict__ stats, const int* __restrict__ seqlen,
    float* __restrict__ out)
{
    const int lane = threadIdx.x;  // one lane per batch
    float score = stats[lane * 8 + 0];
    float logZ  = stats[lane * 8 + 1];
    float accv  = stats[lane * 8 + 2];
    float tpv   = stats[lane * 8 + 3];
    float tnv   = stats[lane * 8 + 4];
    float fpv   = stats[lane * 8 + 5];
    float nll   = logZ - score;
    float slf   = (float)seqlen[lane];
#pragma unroll
    for (int off = 32; off >= 1; off >>= 1) {
        nll  += __shfl_xor(nll,  off, 64);
        accv += __shfl_xor(accv, off, 64);
        tpv  += __shfl_xor(tpv,  off, 64);
        tnv  += __shfl_xor(tnv,  off, 64);
        fpv  += __shfl_xor(fpv,  off, 64);
        slf  += __shfl_xor(slf,  off, 64);
    }
    if (lane == 0) {
        out[NB * BT + 0] = tpv;
        out[NB * BT + 1] = tnv;
        out[NB * BT + 2] = fpv;
        out[NB * BT + 3] = nll / (float)NB;
        out[NB * BT + 4] = accv / slf;
    }
}

extern "C" void kernel_launch(void* const* d_in, const int* in_sizes, int n_in,
                              void* d_out, int out_size, void* d_ws, size_t ws_size,
                              hipStream_t stream)
{
    const float* x      = (const float*)d_in[0];
    const float* W      = (const float*)d_in[1];
    const float* bias   = (const float*)d_in[2];
    const float* trans  = (const float*)d_in[3];
    const int*   label  = (const int*)d_in[4];
    const int*   seqlen = (const int*)d_in[5];
    // d_in[6] = mask: recomputed from seqlen, unused

    float* out    = (float*)d_out;
    float* logits = (float*)d_ws;                  // 64*512*9 floats
    float* stats  = logits + (size_t)NB * BT * NL; // 64*8 floats

    gemm_kernel<<<512, 256, 0, stream>>>(x, W, bias, logits);
    crf_kernel<<<NB / BPB, 1024, 0, stream>>>(logits, trans, label, seqlen, out, stats);
    finalize_kernel<<<1, 64, 0, stream>>>(stats, seqlen, out);
}

// Round 5
// 217.634 us; speedup vs baseline: 1.5453x; 1.5453x over previous
//
#include <hip/hip_runtime.h>
#include <stdint.h>
#include <math.h>

#define NB 64      // batch
#define BT 512     // time steps
#define NH 768     // hidden
#define NL 9       // labels
#define PBT 528    // padded time rows in crf LDS
#define PADW 772   // padded W row stride (floats): (l*772+h)%32 spreads banks
#define NWAVE 2048 // total gemm waves (512 blocks x 4 waves)

__device__ __forceinline__ float rlane(float v, int i) {
    return __int_as_float(__builtin_amdgcn_readlane(__float_as_int(v), i));
}

// DPP-based cross-lane add: v += dpp_move(v); runs on VALU, NOT the DS pipe.
template<int CTRL, int RM>
__device__ __forceinline__ float dppadd(float v) {
    const int t = __builtin_amdgcn_update_dpp(0, __float_as_int(v), CTRL, RM, 0xf, true);
    return v + __int_as_float(t);
}

// full 64-lane sum -> uniform scalar (read from lane 63)
__device__ __forceinline__ float wave_sum_dpp(float v) {
    v = dppadd<0x111, 0xf>(v);   // row_shr:1
    v = dppadd<0x112, 0xf>(v);   // row_shr:2
    v = dppadd<0x114, 0xf>(v);   // row_shr:4
    v = dppadd<0x118, 0xf>(v);   // row_shr:8  -> lane 15 of each row16 = row sum
    v = dppadd<0x142, 0xa>(v);   // row_bcast:15 into rows 1,3
    v = dppadd<0x143, 0xc>(v);   // row_bcast:31 into rows 2,3 -> lane 63 = total
    return rlane(v, 63);
}

// ---------------------------------------------------------------------------
// Kernel 1: logits = x @ W + b.  Wave-per-row; W register-cached from LDS.
// NEW: no occupancy clamp (the old (256,2) capped VGPR at 128 while wr alone
// is 108 -> allocator at the cap, only ~6KB/wave of loads in flight, 1.9TB/s).
// Group-of-4 double-buffered row pipeline: while computing 4 rows, the next
// 4 rows (12KB/wave) are outstanding -> ~96KB/CU in flight, BW-saturating.
// 2048 waves x 16 rows == 32768 rows exactly: no guards, all loops static.
// ---------------------------------------------------------------------------
__global__ __launch_bounds__(256) void gemm_kernel(
    const float* __restrict__ x, const float* __restrict__ W,
    const float* __restrict__ bias, float* __restrict__ logits)
{
    __shared__ float wT[NL * PADW];   // 27.8 KB: W transposed [l][h], padded

    const int tid  = threadIdx.x;
    const int lane = tid & 63;

    // stage W transposed into LDS (coalesced global reads, one-time)
    for (int i = tid; i < NH * NL; i += 256) {
        const int h = i / NL, l = i - h * NL;
        wT[l * PADW + h] = W[i];
    }
    __syncthreads();

    // per-lane register cache: 27 conflict-free ds_read_b128
    float wr[3][NL][4];
#pragma unroll
    for (int k = 0; k < 3; ++k)
#pragma unroll
        for (int l = 0; l < NL; ++l) {
            const float4 w4 = *(const float4*)&wT[l * PADW + k * 256 + lane * 4];
            wr[k][l][0] = w4.x; wr[k][l][1] = w4.y;
            wr[k][l][2] = w4.z; wr[k][l][3] = w4.w;
        }
    const float bj = bias[lane < NL ? lane : 0];

    const int gw = (blockIdx.x * blockDim.x + tid) >> 6;   // 0..2047

    // double-buffered groups of 4 rows; buffer index static after unroll
    float4 buf[2][4][3];
#pragma unroll
    for (int q = 0; q < 4; ++q) {
        const float4* p = (const float4*)(x + (size_t)(gw + q * NWAVE) * NH);
        buf[0][q][0] = p[lane];
        buf[0][q][1] = p[64 + lane];
        buf[0][q][2] = p[128 + lane];
    }

#pragma unroll
    for (int grp = 0; grp < 4; ++grp) {
        const int cb = grp & 1, nb = cb ^ 1;
        if (grp < 3) {
#pragma unroll
            for (int q = 0; q < 4; ++q) {
                const float4* p = (const float4*)(
                    x + (size_t)(gw + ((grp + 1) * 4 + q) * NWAVE) * NH);
                buf[nb][q][0] = p[lane];
                buf[nb][q][1] = p[64 + lane];
                buf[nb][q][2] = p[128 + lane];
            }
        }
#pragma unroll
        for (int q = 0; q < 4; ++q) {
            const float4 a0 = buf[cb][q][0];
            const float4 a1 = buf[cb][q][1];
            const float4 a2 = buf[cb][q][2];
            float acc[NL];
#pragma unroll
            for (int l = 0; l < NL; ++l) {
                float s = a0.x * wr[0][l][0];
                s = fmaf(a0.y, wr[0][l][1], s);
                s = fmaf(a0.z, wr[0][l][2], s);
                s = fmaf(a0.w, wr[0][l][3], s);
                s = fmaf(a1.x, wr[1][l][0], s);
                s = fmaf(a1.y, wr[1][l][1], s);
                s = fmaf(a1.z, wr[1][l][2], s);
                s = fmaf(a1.w, wr[1][l][3], s);
                s = fmaf(a2.x, wr[2][l][0], s);
                s = fmaf(a2.y, wr[2][l][1], s);
                s = fmaf(a2.z, wr[2][l][2], s);
                s = fmaf(a2.w, wr[2][l][3], s);
                acc[l] = s;
            }
            // DPP wave-sum per label -> 9 uniform scalars (VALU only, no DS)
            float sum[NL];
#pragma unroll
            for (int l = 0; l < NL; ++l) sum[l] = wave_sum_dpp(acc[l]);
            // lane j (<9) stores sum[j]: static-index select chain
            float outv = sum[0];
#pragma unroll
            for (int l = 1; l < NL; ++l) outv = (lane == l) ? sum[l] : outv;
            const int row = gw + (grp * 4 + q) * NWAVE;
            if (lane < NL) logits[(size_t)row * NL + lane] = outv + bj;
        }
    }
}

// ---------------------------------------------------------------------------
// Kernel 2: per-batch CRF. Block = 256 (4 waves).  (Round-0 verbatim.)
// ---------------------------------------------------------------------------
__global__ __launch_bounds__(256) void crf_kernel(
    const float* __restrict__ logits, const float* __restrict__ trans,
    const int* __restrict__ label, const int* __restrict__ seqlen,
    float* __restrict__ vit_out, float* __restrict__ stats)
{
    __shared__ __align__(16) float lg_lds[PBT * NL];   // padded, zeros past BT
    __shared__ float    val_lds[BT * NL];              // viterbi alpha vectors
    __shared__ float    trans_lds[NL * NL];
    __shared__ uint8_t  bp_lds[(BT - 1) * NL];
    __shared__ uint64_t packed_lds[BT - 1];
    __shared__ uint8_t  vit_lds[BT];
    __shared__ float    xw[4][4];

    const int b    = blockIdx.x;
    const int tid  = threadIdx.x;
    const int lane = tid & 63;
    const int wv   = tid >> 6;
    const int sl   = seqlen[b];
    const float* lg  = logits + (size_t)b * BT * NL;
    const int*   lab = label + (size_t)b * BT;

    // stage logits (float4) + zero padding + transitions
    {
        const float4* src = (const float4*)lg;
        float4* dst = (float4*)lg_lds;
        for (int idx = tid; idx < BT * NL / 4; idx += 256) dst[idx] = src[idx];
        for (int idx = BT * NL + tid; idx < PBT * NL; idx += 256) lg_lds[idx] = 0.f;
        if (tid < NL * NL) trans_lds[tid] = trans[tid];
    }
    __syncthreads();

    if (wv == 0) {
        // ---- logZ scan, scaled-exp domain ----
        const int j = lane < NL ? lane : 0;
        float E[NL];
#pragma unroll
        for (int i = 0; i < NL; ++i) E[i] = __expf(trans_lds[i * NL + j]) * 0.125f;
        float A = __expf(lg_lds[j]);
        int lc = 0;
        for (int tb = 1; tb < BT + 8; tb += 8) {
            float P[8];
#pragma unroll
            for (int s = 0; s < 8; ++s) P[s] = __expf(lg_lds[(tb + s) * NL + j]);
#pragma unroll
            for (int s = 0; s < 8; ++s) {
                const int t = tb + s;
                const float r0 = rlane(A, 0), r1 = rlane(A, 1), r2 = rlane(A, 2),
                            r3 = rlane(A, 3), r4 = rlane(A, 4), r5 = rlane(A, 5),
                            r6 = rlane(A, 6), r7 = rlane(A, 7), r8 = rlane(A, 8);
                float p0 = r0 * E[0]; p0 = fmaf(r1, E[1], p0); p0 = fmaf(r2, E[2], p0);
                float p1 = r3 * E[3]; p1 = fmaf(r4, E[4], p1); p1 = fmaf(r5, E[5], p1);
                float p2 = r6 * E[6]; p2 = fmaf(r7, E[7], p2); p2 = fmaf(r8, E[8], p2);
                const float An = ((p0 + p1) + p2) * P[s];
                A = (t < sl) ? An : A;
            }
            // exact pow2 renorm: m is positive & normal here.
            const float m = fmaxf(fmaxf(
                fmaxf(fmaxf(rlane(A, 0), rlane(A, 1)), fmaxf(rlane(A, 2), rlane(A, 3))),
                fmaxf(fmaxf(rlane(A, 4), rlane(A, 5)), fmaxf(rlane(A, 6), rlane(A, 7)))),
                rlane(A, 8));
            const int ex = (int)((__float_as_uint(m) >> 23) & 0xFFu) - 126; // frexp exp
            const float sc = __uint_as_float((uint32_t)(127 - ex) << 23);   // 2^-ex
            A *= sc;
            lc += ex;
        }
        const float sum = ((rlane(A, 0) + rlane(A, 1)) + (rlane(A, 2) + rlane(A, 3))) +
                          ((rlane(A, 4) + rlane(A, 5)) + (rlane(A, 6) + rlane(A, 7))) +
                          rlane(A, 8);
        const float logZ = logf(sum) +
            ((float)lc + 3.0f * (float)(sl - 1)) * 0.6931471805599453f;
        if (lane == 0) stats[b * 8 + 1] = logZ;
    } else if (wv == 1) {
        // ---- viterbi value scan; alpha vectors to LDS, argmax deferred ----
        const int j = lane < NL ? lane : 0;
        float tc[NL];
#pragma unroll
        for (int i = 0; i < NL; ++i) tc[i] = trans_lds[i * NL + j];
        float v = lg_lds[j];
        if (lane < NL) val_lds[j] = v;
        for (int tb = 1; tb < BT + 8; tb += 8) {
            float lv[8];
#pragma unroll
            for (int s = 0; s < 8; ++s) lv[s] = lg_lds[(tb + s) * NL + j];
#pragma unroll
            for (int s = 0; s < 8; ++s) {
                const int t = tb + s;
                const float r0 = rlane(v, 0), r1 = rlane(v, 1), r2 = rlane(v, 2),
                            r3 = rlane(v, 3), r4 = rlane(v, 4), r5 = rlane(v, 5),
                            r6 = rlane(v, 6), r7 = rlane(v, 7), r8 = rlane(v, 8);
                const float c0 = r0 + tc[0], c1 = r1 + tc[1], c2 = r2 + tc[2],
                            c3 = r3 + tc[3], c4 = r4 + tc[4], c5 = r5 + tc[5],
                            c6 = r6 + tc[6], c7 = r7 + tc[7], c8 = r8 + tc[8];
                const float m = fmaxf(fmaxf(fmaxf(fmaxf(c0, c1), c2),
                                            fmaxf(fmaxf(c3, c4), c5)),
                                      fmaxf(fmaxf(c6, c7), c8));
                const float nv = m + lv[s];
                v = (t < sl) ? nv : v;
                if (lane < NL && t < BT) val_lds[t * NL + lane] = v;
            }
        }
        // last tag = first-argmax(alphaT)
        const float r0 = rlane(v, 0), r1 = rlane(v, 1), r2 = rlane(v, 2),
                    r3 = rlane(v, 3), r4 = rlane(v, 4), r5 = rlane(v, 5),
                    r6 = rlane(v, 6), r7 = rlane(v, 7), r8 = rlane(v, 8);
        const float m = fmaxf(fmaxf(fmaxf(fmaxf(r0, r1), r2),
                                    fmaxf(fmaxf(r3, r4), r5)),
                              fmaxf(fmaxf(r6, r7), r8));
        const int last = (r0 == m) ? 0 : (r1 == m) ? 1 : (r2 == m) ? 2 :
                         (r3 == m) ? 3 : (r4 == m) ? 4 : (r5 == m) ? 5 :
                         (r6 == m) ? 6 : (r7 == m) ? 7 : 8;
        if (lane == 0) vit_lds[BT - 1] = (uint8_t)last;
    } else if (wv == 2) {
        // ---- gold-path score ----
        float s = 0.f;
        for (int t = lane; t < BT; t += 64) {
            const int lb = lab[t];
            if (t < sl) {
                s += lg_lds[t * NL + lb];
                if (t >= 1) s += trans_lds[lab[t - 1] * NL + lb];
            }
        }
#pragma unroll
        for (int off = 32; off >= 1; off >>= 1) s += __shfl_xor(s, off, 64);
        if (lane == 0) stats[b * 8 + 0] = s;
    }
    __syncthreads();

    // ---- recompute backpointers in parallel (bit-exact first-max) ----
    for (int idx = tid; idx < (BT - 1) * NL; idx += 256) {
        const int tm1 = idx / NL;
        const int jj  = idx - tm1 * NL;
        const int t   = tm1 + 1;
        int bi;
        if (t >= sl) bi = jj;
        else {
            float best = val_lds[tm1 * NL] + trans_lds[jj];
            bi = 0;
#pragma unroll
            for (int i = 1; i < NL; ++i) {
                const float c = val_lds[tm1 * NL + i] + trans_lds[i * NL + jj];
                if (c > best) { best = c; bi = i; }
            }
        }
        bp_lds[idx] = (uint8_t)bi;
    }
    __syncthreads();

    // ---- pack bp rows: 9 x 4 bits -> u64 ----
    for (int r = tid; r < BT - 1; r += 256) {
        uint64_t p = 0;
#pragma unroll
        for (int i = 0; i < NL; ++i)
            p |= (uint64_t)bp_lds[r * NL + i] << (4 * i);
        packed_lds[r] = p;
    }
    __syncthreads();

    // ---- serial backtrack (address-independent LDS reads + 2-op extract) ----
    if (tid == 0) {
        int tag = vit_lds[BT - 1];
        for (int t = BT - 2; t >= 0; --t) {
            const uint64_t row = packed_lds[t];
            tag = (int)((row >> (4 * tag)) & 15u);
            vit_lds[t] = (uint8_t)tag;
        }
    }
    __syncthreads();

    // ---- stats + vit output ----
    float accv = 0.f, tpv = 0.f, tnv = 0.f, fpv = 0.f;
    for (int t = tid; t < BT; t += 256) {
        const int tg = vit_lds[t];
        const int lb = lab[t];
        const bool msk = t < sl;
        vit_out[(size_t)b * BT + t] = (float)tg;
        if (msk && tg == lb) accv += 1.f;
        if (lb > 0 && tg == lb) tpv += 1.f;
        if (lb > 0 && tg != lb) tnv += 1.f;
        if (msk && lb == 0 && tg > 0) fpv += 1.f;
    }
#pragma unroll
    for (int off = 32; off >= 1; off >>= 1) {
        accv += __shfl_xor(accv, off, 64);
        tpv  += __shfl_xor(tpv,  off, 64);
        tnv  += __shfl_xor(tnv,  off, 64);
        fpv  += __shfl_xor(fpv,  off, 64);
    }
    if (lane == 0) { xw[0][wv] = accv; xw[1][wv] = tpv; xw[2][wv] = tnv; xw[3][wv] = fpv; }
    __syncthreads();
    if (tid == 0) {
        stats[b * 8 + 2] = xw[0][0] + xw[0][1] + xw[0][2] + xw[0][3];
        stats[b * 8 + 3] = xw[1][0] + xw[1][1] + xw[1][2] + xw[1][3];
        stats[b * 8 + 4] = xw[2][0] + xw[2][1] + xw[2][2] + xw[2][3];
        stats[b * 8 + 5] = xw[3][0] + xw[3][1] + xw[3][2] + xw[3][3];
    }
}

// ---------------------------------------------------------------------------
// Kernel 3: reduce the 64 per-batch partials -> tp, tn, fp, loss, accuracy
// ---------------------------------------------------------------------------
__global__ __launch_bounds__(64) void finalize_kernel(
    const float* __restrict__ stats, const int* __restrict__ seqlen,
    float* __restrict__ out)
{
    const int lane = threadIdx.x;  // one lane per batch
    float score = stats[lane * 8 + 0];
    float logZ  = stats[lane * 8 + 1];
    float accv  = stats[lane * 8 + 2];
    float tpv   = stats[lane * 8 + 3];
    float tnv   = stats[lane * 8 + 4];
    float fpv   = stats[lane * 8 + 5];
    float nll   = logZ - score;
    float slf   = (float)seqlen[lane];
#pragma unroll
    for (int off = 32; off >= 1; off >>= 1) {
        nll  += __shfl_xor(nll,  off, 64);
        accv += __shfl_xor(accv, off, 64);
        tpv  += __shfl_xor(tpv,  off, 64);
        tnv  += __shfl_xor(tnv,  off, 64);
        fpv  += __shfl_xor(fpv,  off, 64);
        slf  += __shfl_xor(slf,  off, 64);
    }
    if (lane == 0) {
        out[NB * BT + 0] = tpv;
        out[NB * BT + 1] = tnv;
        out[NB * BT + 2] = fpv;
        out[NB * BT + 3] = nll / (float)NB;
        out[NB * BT + 4] = accv / slf;
    }
}

extern "C" void kernel_launch(void* const* d_in, const int* in_sizes, int n_in,
                              void* d_out, int out_size, void* d_ws, size_t ws_size,
                              hipStream_t stream)
{
    const float* x      = (const float*)d_in[0];
    const float* W      = (const float*)d_in[1];
    const float* bias   = (const float*)d_in[2];
    const float* trans  = (const float*)d_in[3];
    const int*   label  = (const int*)d_in[4];
    const int*   seqlen = (const int*)d_in[5];
    // d_in[6] = mask: recomputed from seqlen, unused

    float* out    = (float*)d_out;
    float* logits = (float*)d_ws;                  // 64*512*9 floats
    float* stats  = logits + (size_t)NB * BT * NL; // 64*8 floats

    gemm_kernel<<<512, 256, 0, stream>>>(x, W, bias, logits);
    crf_kernel<<<NB, 256, 0, stream>>>(logits, trans, label, seqlen, out, stats);
    finalize_kernel<<<1, 64, 0, stream>>>(stats, seqlen, out);
}